// Round 1
// baseline (2261.849 us; speedup 1.0000x reference)
//
#include <hip/hip_runtime.h>
#include <math.h>

#define NEGINF (-INFINITY)
constexpr int Np = 4096;
constexpr int Kn = 20;
constexpr float EPSf = 1e-5f;
constexpr float SLOPE = 0.2f;

// insertion into a register-resident sorted (desc) top-20 list
__device__ __forceinline__ void topk_insert(float (&lv)[20], int (&li)[20], float v, int j) {
  if (v > lv[19]) {
    float cv = v; int ci = j;
#pragma unroll
    for (int s = 0; s < 20; ++s) {
      bool sw = cv > lv[s];
      float tv = lv[s]; int ti = li[s];
      lv[s] = sw ? cv : lv[s]; li[s] = sw ? ci : li[s];
      cv = sw ? tv : cv;       ci = sw ? ti : ci;
    }
  }
}

// ---------------- K1: knn over 2-D coords + edgeconv1 (one wave per point) ----------------
__global__ __launch_bounds__(256) void k1_knn1_edge1(
    const float* __restrict__ x, const float* __restrict__ W1,
    const float* __restrict__ g1, const float* __restrict__ b1,
    const float* __restrict__ m1, const float* __restrict__ v1,
    float* __restrict__ x1, float* __restrict__ x1t, float* __restrict__ xx2)
{
  __shared__ float2 sxy[Np];
  __shared__ int stopidx[4][Kn];
  const int b = blockIdx.y;
  const int tid = threadIdx.x;
  const int w = tid >> 6, L = tid & 63;
  const int n = blockIdx.x * 4 + w;

  for (int j = tid; j < Np; j += 256)
    sxy[j] = make_float2(x[b*2*Np + j], x[b*2*Np + Np + j]);
  __syncthreads();

  const float2 cp = sxy[n];
  const float cx0 = cp.x, cx1 = cp.y;
  const float xxc = cx0*cx0 + cx1*cx1;

  float d[64];
#pragma unroll
  for (int t = 0; t < 64; ++t) {
    int j = t*64 + L;
    float2 pj = sxy[j];
    float xxj = pj.x*pj.x + pj.y*pj.y;
    float dot = cx0*pj.x + cx1*pj.y;
    float inner = -2.0f*dot;
    d[t] = (-xxc - inner) - xxj;
  }

  for (int kk = 0; kk < Kn; ++kk) {
    float bv = d[0]; int bj = L;
#pragma unroll
    for (int t = 1; t < 64; ++t) {
      int j = t*64 + L;
      if (d[t] > bv) { bv = d[t]; bj = j; }
    }
#pragma unroll
    for (int off = 1; off < 64; off <<= 1) {
      float ov = __shfl_xor(bv, off);
      int oj = __shfl_xor(bj, off);
      if (ov > bv || (ov == bv && oj < bj)) { bv = ov; bj = oj; }
    }
    if (L == 0) stopidx[w][kk] = bj;
    int mt = bj >> 6, ml = bj & 63;
    if (L == ml) {
#pragma unroll
      for (int t = 0; t < 64; ++t) if (t == mt) d[t] = NEGINF;
    }
  }

  // edgeconv1: lane = output channel o
  const int o = L;
  const float4 w1v = reinterpret_cast<const float4*>(W1)[o];
  const float sc = g1[o] / sqrtf(v1[o] + EPSf);
  const float mo = m1[o], bo = b1[o];
  float xm = NEGINF;
  for (int k = 0; k < Kn; ++k) {
    int j = stopidx[w][k];
    float2 pj = sxy[j];
    float vv = w1v.x*(pj.x-cx0) + w1v.y*(pj.y-cx1) + w1v.z*cx0 + w1v.w*cx1;
    float h = (vv - mo)*sc + bo;
    h = h >= 0.f ? h : SLOPE*h;
    xm = fmaxf(xm, h);
  }
  x1[(b*64 + o)*Np + n] = xm;
  x1t[(b*Np + n)*64 + o] = xm;
  float s = xm*xm;
#pragma unroll
  for (int off = 1; off < 64; off <<= 1) s += __shfl_xor(s, off);
  if (L == 0) xx2[b*Np + n] = s;
}

// ---------------- K2: knn over 64-D features, fused gram + streaming top-k ----------------
__global__ __launch_bounds__(256) void k2_knn2(
    const float* __restrict__ x1, const float* __restrict__ xx2,
    int* __restrict__ idx2)
{
  __shared__ float rowfeat[16][68];     // padded
  __shared__ float colfeat[32][256];    // one 32-channel half of a 256-col tile
  __shared__ float dtile[16][260];      // padded
  __shared__ float colxx[256];
  __shared__ float rowxx[16];
  __shared__ float thrsh[16];
  __shared__ float bvbuf[16][64];
  __shared__ int   bibuf[16][64];
  __shared__ int   cnt[16];

  const int b = blockIdx.y;
  const int n0 = blockIdx.x * 16;
  const int tid = threadIdx.x;
  const int rg = tid >> 6, L = tid & 63;
  const int frow = tid >> 4, fl = tid & 15;
  const bool ismerge = (fl == 0);

  for (int idx = tid; idx < 16*64; idx += 256) {
    int r = idx >> 6, c = idx & 63;
    rowfeat[r][c] = x1[(b*64 + c)*Np + n0 + r];
  }
  if (tid < 16) { rowxx[tid] = xx2[b*Np + n0 + tid]; thrsh[tid] = NEGINF; cnt[tid] = 0; }

  float lv[20]; int li[20];
#pragma unroll
  for (int s = 0; s < 20; ++s) { lv[s] = NEGINF; li[s] = 0; }

  for (int tt = 0; tt < 16; ++tt) {
    const int jg = tt * 256;
    float acc[4][4];
#pragma unroll
    for (int q = 0; q < 4; ++q) { acc[q][0]=0.f; acc[q][1]=0.f; acc[q][2]=0.f; acc[q][3]=0.f; }

    for (int h = 0; h < 2; ++h) {
      __syncthreads();
      const int c0 = h * 32;
#pragma unroll
      for (int it = 0; it < 8; ++it) {
        int cc = it*4 + (tid >> 6);
        int j = (tid & 63) * 4;
        float4 vx = *reinterpret_cast<const float4*>(&x1[(b*64 + c0 + cc)*Np + jg + j]);
        *reinterpret_cast<float4*>(&colfeat[cc][j]) = vx;
      }
      if (h == 0 && tid < 64) {
        float4 vv = *reinterpret_cast<const float4*>(&xx2[b*Np + jg + tid*4]);
        *reinterpret_cast<float4*>(&colxx[tid*4]) = vv;
      }
      __syncthreads();
#pragma unroll
      for (int c4 = 0; c4 < 8; ++c4) {
        float4 cw0 = *reinterpret_cast<const float4*>(&colfeat[c4*4+0][L*4]);
        float4 cw1 = *reinterpret_cast<const float4*>(&colfeat[c4*4+1][L*4]);
        float4 cw2 = *reinterpret_cast<const float4*>(&colfeat[c4*4+2][L*4]);
        float4 cw3 = *reinterpret_cast<const float4*>(&colfeat[c4*4+3][L*4]);
#pragma unroll
        for (int q = 0; q < 4; ++q) {
          float4 rw = *reinterpret_cast<const float4*>(&rowfeat[rg*4+q][c0 + c4*4]);
          acc[q][0] += rw.x*cw0.x + rw.y*cw1.x + rw.z*cw2.x + rw.w*cw3.x;
          acc[q][1] += rw.x*cw0.y + rw.y*cw1.y + rw.z*cw2.y + rw.w*cw3.y;
          acc[q][2] += rw.x*cw0.z + rw.y*cw1.z + rw.z*cw2.z + rw.w*cw3.z;
          acc[q][3] += rw.x*cw0.w + rw.y*cw1.w + rw.z*cw2.w + rw.w*cw3.w;
        }
      }
    }

    // pd = -xx_i - (-2*dot) - xx_j, write tile of distances
#pragma unroll
    for (int q = 0; q < 4; ++q) {
      int r = rg*4 + q;
      float xr = rowxx[r];
      float4 o4;
      o4.x = (-xr - (-2.0f*acc[q][0])) - colxx[L*4+0];
      o4.y = (-xr - (-2.0f*acc[q][1])) - colxx[L*4+1];
      o4.z = (-xr - (-2.0f*acc[q][2])) - colxx[L*4+2];
      o4.w = (-xr - (-2.0f*acc[q][3])) - colxx[L*4+3];
      *reinterpret_cast<float4*>(&dtile[r][L*4]) = o4;
    }
    __syncthreads();

    if (tt == 0) {
      if (ismerge) {
        for (int j = 0; j < 256; ++j) topk_insert(lv, li, dtile[frow][j], jg + j);
        thrsh[frow] = lv[19];
      }
    } else {
      float th = thrsh[frow];
#pragma unroll
      for (int t = 0; t < 16; ++t) {
        int j = fl + t*16;
        float v = dtile[frow][j];
        if (v > th) {
          int pos = atomicAdd(&cnt[frow], 1);
          if (pos < 64) { bvbuf[frow][pos] = v; bibuf[frow][pos] = jg + j; }
        }
      }
      __syncthreads();
      if (ismerge) {
        int c = cnt[frow];
        if (c >= 64) {
          for (int j = 0; j < 256; ++j) topk_insert(lv, li, dtile[frow][j], jg + j);
        } else {
          for (int s0 = 0; s0 < c; ++s0) topk_insert(lv, li, bvbuf[frow][s0], bibuf[frow][s0]);
        }
        thrsh[frow] = lv[19];
        cnt[frow] = 0;
      }
    }
    __syncthreads();
  }

  if (ismerge) {
#pragma unroll
    for (int k = 0; k < Kn; ++k) idx2[(b*Np + n0 + frow)*Kn + k] = li[k];
  }
}

// ---------------- K3: edgeconv2 (one wave per point, W2 rows in registers) ----------------
__global__ __launch_bounds__(256) void k3_edge2(
    const float* __restrict__ x1t, const int* __restrict__ idx2,
    const float* __restrict__ W2,
    const float* __restrict__ g2, const float* __restrict__ b2,
    const float* __restrict__ m2, const float* __restrict__ v2,
    float* __restrict__ x2)
{
  __shared__ float scen[4][64];
  __shared__ float snbr[4][64];
  const int b = blockIdx.y;
  const int tid = threadIdx.x;
  const int w = tid >> 6, L = tid & 63;
  const int n = blockIdx.x*4 + w;

  float4 w2a[16], w2b[16];
#pragma unroll
  for (int q = 0; q < 16; ++q) {
    w2a[q] = reinterpret_cast<const float4*>(W2 + L*128)[q];
    w2b[q] = reinterpret_cast<const float4*>(W2 + L*128 + 64)[q];
  }
  const float sc2 = g2[L]/sqrtf(v2[L]+EPSf);
  const float m2o = m2[L], b2o = b2[L];

  scen[w][L] = x1t[(b*Np + n)*64 + L];
  float u = 0.f, t2 = 0.f;
#pragma unroll
  for (int q = 0; q < 16; ++q) {
    float4 cv = *reinterpret_cast<const float4*>(&scen[w][q*4]);
    u  += w2a[q].x*cv.x + w2a[q].y*cv.y + w2a[q].z*cv.z + w2a[q].w*cv.w;
    t2 += w2b[q].x*cv.x + w2b[q].y*cv.y + w2b[q].z*cv.z + w2b[q].w*cv.w;
  }

  const int* ip = idx2 + (b*Np + n)*Kn;
  float xm = NEGINF;
  float cur = x1t[(b*Np + ip[0])*64 + L];
  for (int k = 0; k < Kn; ++k) {
    float nxt = 0.f;
    if (k+1 < Kn) nxt = x1t[(b*Np + ip[k+1])*64 + L];
    snbr[w][L] = cur;
    float a = 0.f;
#pragma unroll
    for (int q = 0; q < 16; ++q) {
      float4 nv = *reinterpret_cast<const float4*>(&snbr[w][q*4]);
      a += w2a[q].x*nv.x + w2a[q].y*nv.y + w2a[q].z*nv.z + w2a[q].w*nv.w;
    }
    float vv = a - u + t2;
    float hh = (vv - m2o)*sc2 + b2o;
    hh = hh >= 0.f ? hh : SLOPE*hh;
    xm = fmaxf(xm, hh);
    cur = nxt;
  }
  x2[(b*64 + L)*Np + n] = xm;
}

// ---------------- K4: conv5 + per-wave max over n ----------------
__global__ __launch_bounds__(256) void k4_conv5max(
    const float* __restrict__ x1, const float* __restrict__ x2,
    const float* __restrict__ W5,
    const float* __restrict__ g5, const float* __restrict__ b5,
    const float* __restrict__ m5, const float* __restrict__ v5,
    float* __restrict__ partials)  // (B,128,64)
{
  const int b = blockIdx.y;
  const int tid = threadIdx.x;
  const int n = blockIdx.x*256 + tid;
  const int waveid = blockIdx.x*4 + (tid >> 6);
  float xcr[128];
#pragma unroll
  for (int c = 0; c < 64; ++c) {
    xcr[c]    = x1[(b*64 + c)*Np + n];
    xcr[64+c] = x2[(b*64 + c)*Np + n];
  }
  for (int o = 0; o < 128; ++o) {
    const float* wr = W5 + o*128;
    float dot = 0.f;
#pragma unroll
    for (int c = 0; c < 128; c += 4) {
      float4 wv = *reinterpret_cast<const float4*>(wr + c);
      dot += wv.x*xcr[c] + wv.y*xcr[c+1] + wv.z*xcr[c+2] + wv.w*xcr[c+3];
    }
    float hv = (dot - m5[o])*(g5[o]/sqrtf(v5[o]+EPSf)) + b5[o];
    hv = hv >= 0.f ? hv : SLOPE*hv;
#pragma unroll
    for (int off = 1; off < 64; off <<= 1) hv = fmaxf(hv, __shfl_xor(hv, off));
    if ((tid & 63) == 0) partials[(b*128 + o)*64 + waveid] = hv;
  }
}

// ---------------- K5: reduce partial maxima -> gmax, then t6 = W6a * gmax ----------------
__global__ __launch_bounds__(256) void k5_reduce_t6(
    const float* __restrict__ partials, const float* __restrict__ W6,
    float* __restrict__ t6)  // (B,256)
{
  __shared__ float sg[128];
  const int b = blockIdx.x;
  const int tid = threadIdx.x;
  if (tid < 128) {
    float m = NEGINF;
    for (int w = 0; w < 64; ++w) m = fmaxf(m, partials[(b*128 + tid)*64 + w]);
    sg[tid] = m;
  }
  __syncthreads();
  float a = 0.f;
#pragma unroll
  for (int c = 0; c < 128; c += 4) {
    float4 wv = *reinterpret_cast<const float4*>(W6 + tid*256 + c);
    a += wv.x*sg[c] + wv.y*sg[c+1] + wv.z*sg[c+2] + wv.w*sg[c+3];
  }
  t6[b*256 + tid] = a;
}

// ---------------- K6: conv6 (W6b part + t6) + bn + lrelu + W9 dot ----------------
__global__ __launch_bounds__(256) void k6_conv6_out(
    const float* __restrict__ x1, const float* __restrict__ x2,
    const float* __restrict__ W6, const float* __restrict__ t6,
    const float* __restrict__ g6, const float* __restrict__ b6,
    const float* __restrict__ m6, const float* __restrict__ v6,
    const float* __restrict__ W9,
    float* __restrict__ out)
{
  const int b = blockIdx.y;
  const int tid = threadIdx.x;
  const int n = blockIdx.x*256 + tid;
  float xcr[128];
#pragma unroll
  for (int c = 0; c < 64; ++c) {
    xcr[c]    = x1[(b*64 + c)*Np + n];
    xcr[64+c] = x2[(b*64 + c)*Np + n];
  }
  float oacc = 0.f;
  for (int o = 0; o < 256; ++o) {
    const float* wr = W6 + o*256 + 128;
    float dot = t6[b*256 + o];
#pragma unroll
    for (int c = 0; c < 128; c += 4) {
      float4 wv = *reinterpret_cast<const float4*>(wr + c);
      dot += wv.x*xcr[c] + wv.y*xcr[c+1] + wv.z*xcr[c+2] + wv.w*xcr[c+3];
    }
    float hv = (dot - m6[o])*(g6[o]/sqrtf(v6[o]+EPSf)) + b6[o];
    hv = hv >= 0.f ? hv : SLOPE*hv;
    oacc += W9[o]*hv;
  }
  out[b*Np + n] = oacc;
}

extern "C" void kernel_launch(void* const* d_in, const int* in_sizes, int n_in,
                              void* d_out, int out_size, void* d_ws, size_t ws_size,
                              hipStream_t stream) {
  const float* x  = (const float*)d_in[0];
  const float* W1 = (const float*)d_in[1];
  const float* g1 = (const float*)d_in[2];
  const float* b1 = (const float*)d_in[3];
  const float* m1 = (const float*)d_in[4];
  const float* v1 = (const float*)d_in[5];
  const float* W2 = (const float*)d_in[6];
  const float* g2 = (const float*)d_in[7];
  const float* b2 = (const float*)d_in[8];
  const float* m2 = (const float*)d_in[9];
  const float* v2 = (const float*)d_in[10];
  const float* W5 = (const float*)d_in[11];
  const float* g5 = (const float*)d_in[12];
  const float* b5 = (const float*)d_in[13];
  const float* m5 = (const float*)d_in[14];
  const float* v5 = (const float*)d_in[15];
  const float* W6 = (const float*)d_in[16];
  const float* g6 = (const float*)d_in[17];
  const float* b6 = (const float*)d_in[18];
  const float* m6 = (const float*)d_in[19];
  const float* v6 = (const float*)d_in[20];
  const float* W9 = (const float*)d_in[21];
  float* out = (float*)d_out;

  float* F = (float*)d_ws;
  float* x1    = F;                  // 4*64*4096 = 1048576
  float* x1t   = F + 1048576;        // 1048576
  float* x2    = F + 2097152;        // 1048576
  float* xx2   = F + 3145728;        // 16384
  float* t6    = F + 3162112;        // 1024
  float* parts = F + 3163136;        // 4*128*64 = 32768
  int*   idx2  = (int*)(F + 3195904);// 4*4096*20 ints

  k1_knn1_edge1<<<dim3(1024,4), 256, 0, stream>>>(x, W1, g1, b1, m1, v1, x1, x1t, xx2);
  k2_knn2<<<dim3(256,4), 256, 0, stream>>>(x1, xx2, idx2);
  k3_edge2<<<dim3(1024,4), 256, 0, stream>>>(x1t, idx2, W2, g2, b2, m2, v2, x2);
  k4_conv5max<<<dim3(16,4), 256, 0, stream>>>(x1, x2, W5, g5, b5, m5, v5, parts);
  k5_reduce_t6<<<4, 256, 0, stream>>>(parts, W6, t6);
  k6_conv6_out<<<dim3(16,4), 256, 0, stream>>>(x1, x2, W6, t6, g6, b6, m6, v6, W9, out);
}

// Round 2
// 1178.184 us; speedup vs baseline: 1.9198x; 1.9198x over previous
//
#include <hip/hip_runtime.h>
#include <math.h>

#define NEGINF (-INFINITY)
constexpr int Np = 4096;
constexpr int Kn = 20;
constexpr float EPSf = 1e-5f;
constexpr float SLOPE = 0.2f;

typedef __bf16 bf16x8 __attribute__((ext_vector_type(8)));
typedef float f32x4 __attribute__((ext_vector_type(4)));

// insertion into a register-resident sorted (desc) top-20 list
__device__ __forceinline__ void topk_insert(float (&lv)[20], int (&li)[20], float v, int j) {
  if (v > lv[19]) {
    float cv = v; int ci = j;
#pragma unroll
    for (int s = 0; s < 20; ++s) {
      bool sw = cv > lv[s];
      float tv = lv[s]; int ti = li[s];
      lv[s] = sw ? cv : lv[s]; li[s] = sw ? ci : li[s];
      cv = sw ? tv : cv;       ci = sw ? ti : ci;
    }
  }
}

// ---------------- K1: knn over 2-D coords + edgeconv1 (one wave per point) ----------------
__global__ __launch_bounds__(256) void k1_knn1_edge1(
    const float* __restrict__ x, const float* __restrict__ W1,
    const float* __restrict__ g1, const float* __restrict__ b1,
    const float* __restrict__ m1, const float* __restrict__ v1,
    float* __restrict__ x1, __bf16* __restrict__ x1h, __bf16* __restrict__ x1l,
    float* __restrict__ xx2)
{
  __shared__ float2 sxy[Np];
  __shared__ int stopidx[4][Kn];
  const int b = blockIdx.y;
  const int tid = threadIdx.x;
  const int w = tid >> 6, L = tid & 63;
  const int n = blockIdx.x * 4 + w;

  for (int j = tid; j < Np; j += 256)
    sxy[j] = make_float2(x[b*2*Np + j], x[b*2*Np + Np + j]);
  __syncthreads();

  const float2 cp = sxy[n];
  const float cx0 = cp.x, cx1 = cp.y;
  const float xxc = cx0*cx0 + cx1*cx1;

  float d[64];
#pragma unroll
  for (int t = 0; t < 64; ++t) {
    int j = t*64 + L;
    float2 pj = sxy[j];
    float xxj = pj.x*pj.x + pj.y*pj.y;
    float dot = cx0*pj.x + cx1*pj.y;
    float inner = -2.0f*dot;
    d[t] = (-xxc - inner) - xxj;
  }

  for (int kk = 0; kk < Kn; ++kk) {
    float bv = d[0]; int bj = L;
#pragma unroll
    for (int t = 1; t < 64; ++t) {
      int j = t*64 + L;
      if (d[t] > bv) { bv = d[t]; bj = j; }
    }
#pragma unroll
    for (int off = 1; off < 64; off <<= 1) {
      float ov = __shfl_xor(bv, off);
      int oj = __shfl_xor(bj, off);
      if (ov > bv || (ov == bv && oj < bj)) { bv = ov; bj = oj; }
    }
    if (L == 0) stopidx[w][kk] = bj;
    int mt = bj >> 6, ml = bj & 63;
    if (L == ml) {
#pragma unroll
      for (int t = 0; t < 64; ++t) if (t == mt) d[t] = NEGINF;
    }
  }

  // edgeconv1: lane = output channel o
  const int o = L;
  const float4 w1v = reinterpret_cast<const float4*>(W1)[o];
  const float sc = g1[o] / sqrtf(v1[o] + EPSf);
  const float mo = m1[o], bo = b1[o];
  float xm = NEGINF;
  for (int k = 0; k < Kn; ++k) {
    int j = stopidx[w][k];
    float2 pj = sxy[j];
    float vv = w1v.x*(pj.x-cx0) + w1v.y*(pj.y-cx1) + w1v.z*cx0 + w1v.w*cx1;
    float h = (vv - mo)*sc + bo;
    h = h >= 0.f ? h : SLOPE*h;
    xm = fmaxf(xm, h);
  }
  x1[(b*64 + o)*Np + n] = xm;
  __bf16 hb = (__bf16)xm;
  float hf = (float)hb;
  __bf16 lb = (__bf16)(xm - hf);
  size_t tbase = ((size_t)b*Np + n)*64 + o;
  x1h[tbase] = hb;
  x1l[tbase] = lb;
  float s = xm*xm;
#pragma unroll
  for (int off = 1; off < 64; off <<= 1) s += __shfl_xor(s, off);
  if (L == 0) xx2[b*Np + n] = s;
}

// ---------------- K2: knn2 via split-bf16 MFMA gram + distributed streaming top-k -------
// grid (256 rowblocks, 2 col-halves, 4 batches), 64 threads (1 wave).
// Ranks by e = 2*dot(x_i,x_j) - ||x_j||^2 (equivalent to pd up to per-row constant).
__global__ __launch_bounds__(64) void k2_knn2(
    const __bf16* __restrict__ xh, const __bf16* __restrict__ xl,
    const float* __restrict__ xx2,
    float* __restrict__ cand_v, int* __restrict__ cand_i)
{
  __shared__ float e[16][68];
  __shared__ float sxx[64];
  __shared__ float mv[16][4][20];
  __shared__ int   mi[16][4][20];

  const int b = blockIdx.z;
  const int half = blockIdx.y;
  const int n0 = blockIdx.x * 16;
  const int L = threadIdx.x;
  const int L15 = L & 15, quad = L >> 4;

  // A fragments: rows n0..n0+15, lane holds A[m=L15][k=quad*8+j], chunks k0=0,32
  const __bf16* Abase_h = xh + ((size_t)b*Np + n0)*64;
  const __bf16* Abase_l = xl + ((size_t)b*Np + n0)*64;
  bf16x8 ah0 = *reinterpret_cast<const bf16x8*>(Abase_h + L15*64 +  0 + quad*8);
  bf16x8 ah1 = *reinterpret_cast<const bf16x8*>(Abase_h + L15*64 + 32 + quad*8);
  bf16x8 al0 = *reinterpret_cast<const bf16x8*>(Abase_l + L15*64 +  0 + quad*8);
  bf16x8 al1 = *reinterpret_cast<const bf16x8*>(Abase_l + L15*64 + 32 + quad*8);

  float lv[20]; int li[20];
#pragma unroll
  for (int s = 0; s < 20; ++s) { lv[s] = NEGINF; li[s] = 0; }

  const int srow = L >> 2, sst = L & 3;   // scan assignment: row, 16-col stripe

  for (int tt = 0; tt < 32; ++tt) {
    const int colbase = half*2048 + tt*64;
    __syncthreads();                       // prev scan done before overwriting sxx/e
    sxx[L] = xx2[b*Np + colbase + L];

    // B fragments: cols colbase + s*16 + L15, B[k=quad*8+j][n=L15]
    const __bf16* Bh = xh + ((size_t)b*Np + colbase)*64;
    const __bf16* Bl = xl + ((size_t)b*Np + colbase)*64;
    bf16x8 bh[4][2], bl[4][2];
#pragma unroll
    for (int s = 0; s < 4; ++s) {
#pragma unroll
      for (int c = 0; c < 2; ++c) {
        bh[s][c] = *reinterpret_cast<const bf16x8*>(Bh + (s*16 + L15)*64 + c*32 + quad*8);
        bl[s][c] = *reinterpret_cast<const bf16x8*>(Bl + (s*16 + L15)*64 + c*32 + quad*8);
      }
    }

    f32x4 acc[4];
#pragma unroll
    for (int s = 0; s < 4; ++s) {
      acc[s] = (f32x4){0.f, 0.f, 0.f, 0.f};
      acc[s] = __builtin_amdgcn_mfma_f32_16x16x32_bf16(ah0, bh[s][0], acc[s], 0, 0, 0);
      acc[s] = __builtin_amdgcn_mfma_f32_16x16x32_bf16(ah1, bh[s][1], acc[s], 0, 0, 0);
      acc[s] = __builtin_amdgcn_mfma_f32_16x16x32_bf16(ah0, bl[s][0], acc[s], 0, 0, 0);
      acc[s] = __builtin_amdgcn_mfma_f32_16x16x32_bf16(ah1, bl[s][1], acc[s], 0, 0, 0);
      acc[s] = __builtin_amdgcn_mfma_f32_16x16x32_bf16(al0, bh[s][0], acc[s], 0, 0, 0);
      acc[s] = __builtin_amdgcn_mfma_f32_16x16x32_bf16(al1, bh[s][1], acc[s], 0, 0, 0);
    }

    __syncthreads();                       // sxx visible
    // C/D layout: col = L15, row = quad*4 + reg
#pragma unroll
    for (int s = 0; s < 4; ++s) {
      float xc = sxx[s*16 + L15];
#pragma unroll
      for (int r = 0; r < 4; ++r)
        e[quad*4 + r][s*16 + L15] = 2.0f*acc[s][r] - xc;
    }
    __syncthreads();                       // e visible

    // streaming top-k scan: lane = (row srow, stripe sst of 16 cols)
    const int cb = colbase + sst*16;
#pragma unroll
    for (int tq = 0; tq < 4; ++tq) {
      float4 rv = *reinterpret_cast<const float4*>(&e[srow][sst*16 + tq*4]);
      int jb = cb + tq*4;
      topk_insert(lv, li, rv.x, jb);
      topk_insert(lv, li, rv.y, jb+1);
      topk_insert(lv, li, rv.z, jb+2);
      topk_insert(lv, li, rv.w, jb+3);
    }
  }

  // dump per-lane lists, merge 4 stripes per row
#pragma unroll
  for (int k = 0; k < Kn; ++k) { mv[srow][sst][k] = lv[k]; mi[srow][sst][k] = li[k]; }
  __syncthreads();
  if (L < 16) {
    const int r = L;
    int p0 = 0, p1 = 0, p2 = 0, p3 = 0;
    size_t obase = (((size_t)b*Np + n0 + r)*2 + half)*Kn;
    for (int k = 0; k < Kn; ++k) {
      float v0 = (p0 < 20) ? mv[r][0][p0] : NEGINF; int i0 = (p0 < 20) ? mi[r][0][p0] : 0x7fffffff;
      float v1 = (p1 < 20) ? mv[r][1][p1] : NEGINF; int i1 = (p1 < 20) ? mi[r][1][p1] : 0x7fffffff;
      float v2 = (p2 < 20) ? mv[r][2][p2] : NEGINF; int i2 = (p2 < 20) ? mi[r][2][p2] : 0x7fffffff;
      float v3 = (p3 < 20) ? mv[r][3][p3] : NEGINF; int i3 = (p3 < 20) ? mi[r][3][p3] : 0x7fffffff;
      int sel = 0; float bv = v0; int bi = i0;
      if (v1 > bv || (v1 == bv && i1 < bi)) { sel = 1; bv = v1; bi = i1; }
      if (v2 > bv || (v2 == bv && i2 < bi)) { sel = 2; bv = v2; bi = i2; }
      if (v3 > bv || (v3 == bv && i3 < bi)) { sel = 3; bv = v3; bi = i3; }
      cand_v[obase + k] = bv;
      cand_i[obase + k] = bi;
      p0 += (sel == 0); p1 += (sel == 1); p2 += (sel == 2); p3 += (sel == 3);
    }
  }
}

// ---------------- K2b: merge the two col-half candidate lists per row ----------------
__global__ __launch_bounds__(256) void k2b_merge(
    const float* __restrict__ cand_v, const int* __restrict__ cand_i,
    int* __restrict__ idx2)
{
  const int row = blockIdx.x*256 + threadIdx.x;   // b*Np + n
  const float* v0p = cand_v + (size_t)row*2*Kn;
  const int*   i0p = cand_i + (size_t)row*2*Kn;
  int p0 = 0, p1 = 0;
  for (int k = 0; k < Kn; ++k) {
    float v0 = (p0 < Kn) ? v0p[p0] : NEGINF;      int i0 = (p0 < Kn) ? i0p[p0] : 0x7fffffff;
    float v1 = (p1 < Kn) ? v0p[Kn + p1] : NEGINF; int i1 = (p1 < Kn) ? i0p[Kn + p1] : 0x7fffffff;
    bool t1 = (v1 > v0) || (v1 == v0 && i1 < i0);
    idx2[(size_t)row*Kn + k] = t1 ? i1 : i0;
    p0 += !t1; p1 += t1;
  }
}

// ---------------- K3: edgeconv2 (one wave per point, W2 rows in registers) ----------------
__global__ __launch_bounds__(256) void k3_edge2(
    const __bf16* __restrict__ xh, const __bf16* __restrict__ xl,
    const int* __restrict__ idx2,
    const float* __restrict__ W2,
    const float* __restrict__ g2, const float* __restrict__ b2,
    const float* __restrict__ m2, const float* __restrict__ v2,
    float* __restrict__ x2)
{
  __shared__ float scen[4][64];
  __shared__ float snbr[4][64];
  const int b = blockIdx.y;
  const int tid = threadIdx.x;
  const int w = tid >> 6, L = tid & 63;
  const int n = blockIdx.x*4 + w;

  float4 w2a[16], w2b[16];
#pragma unroll
  for (int q = 0; q < 16; ++q) {
    w2a[q] = reinterpret_cast<const float4*>(W2 + L*128)[q];
    w2b[q] = reinterpret_cast<const float4*>(W2 + L*128 + 64)[q];
  }
  const float sc2 = g2[L]/sqrtf(v2[L]+EPSf);
  const float m2o = m2[L], b2o = b2[L];

  float cen = (float)xh[((size_t)b*Np + n)*64 + L] + (float)xl[((size_t)b*Np + n)*64 + L];
  scen[w][L] = cen;
  __syncthreads();
  float u = 0.f, t2 = 0.f;
#pragma unroll
  for (int q = 0; q < 16; ++q) {
    float4 cv = *reinterpret_cast<const float4*>(&scen[w][q*4]);
    u  += w2a[q].x*cv.x + w2a[q].y*cv.y + w2a[q].z*cv.z + w2a[q].w*cv.w;
    t2 += w2b[q].x*cv.x + w2b[q].y*cv.y + w2b[q].z*cv.z + w2b[q].w*cv.w;
  }

  const int* ip = idx2 + ((size_t)b*Np + n)*Kn;
  float xm = NEGINF;
  int j0 = ip[0];
  float cur = (float)xh[((size_t)b*Np + j0)*64 + L] + (float)xl[((size_t)b*Np + j0)*64 + L];
  for (int k = 0; k < Kn; ++k) {
    float nxt = 0.f;
    if (k+1 < Kn) {
      int jn = ip[k+1];
      nxt = (float)xh[((size_t)b*Np + jn)*64 + L] + (float)xl[((size_t)b*Np + jn)*64 + L];
    }
    snbr[w][L] = cur;
    float a = 0.f;
#pragma unroll
    for (int q = 0; q < 16; ++q) {
      float4 nv = *reinterpret_cast<const float4*>(&snbr[w][q*4]);
      a += w2a[q].x*nv.x + w2a[q].y*nv.y + w2a[q].z*nv.z + w2a[q].w*nv.w;
    }
    float vv = a - u + t2;
    float hh = (vv - m2o)*sc2 + b2o;
    hh = hh >= 0.f ? hh : SLOPE*hh;
    xm = fmaxf(xm, hh);
    cur = nxt;
  }
  x2[(b*64 + L)*Np + n] = xm;
}

// ---------------- K4: conv5 + per-block max over n ----------------
// grid (64 nblocks, 4 b), 256 thr: p = tid&63 (point), wave g = o-group of 32
__global__ __launch_bounds__(256) void k4_conv5max(
    const float* __restrict__ x1, const float* __restrict__ x2,
    const float* __restrict__ W5,
    const float* __restrict__ g5, const float* __restrict__ b5,
    const float* __restrict__ m5, const float* __restrict__ v5,
    float* __restrict__ partials)  // (B,128,64)
{
  const int b = blockIdx.y, nb = blockIdx.x;
  const int tid = threadIdx.x;
  const int p = tid & 63;
  const int g = __builtin_amdgcn_readfirstlane(tid >> 6);
  const int n = nb*64 + p;
  float xcr[128];
#pragma unroll
  for (int c = 0; c < 64; ++c) {
    xcr[c]    = x1[(b*64 + c)*Np + n];
    xcr[64+c] = x2[(b*64 + c)*Np + n];
  }
  for (int oi = 0; oi < 32; ++oi) {
    const int o = g*32 + oi;
    const float* wr = W5 + o*128;
    float dot = 0.f;
#pragma unroll
    for (int c = 0; c < 128; c += 4) {
      float4 wv = *reinterpret_cast<const float4*>(wr + c);
      dot += wv.x*xcr[c] + wv.y*xcr[c+1] + wv.z*xcr[c+2] + wv.w*xcr[c+3];
    }
    float hv = (dot - m5[o])*(g5[o]/sqrtf(v5[o]+EPSf)) + b5[o];
    hv = hv >= 0.f ? hv : SLOPE*hv;
#pragma unroll
    for (int off = 1; off < 64; off <<= 1) hv = fmaxf(hv, __shfl_xor(hv, off));
    if (p == 0) partials[(b*128 + o)*64 + nb] = hv;
  }
}

// ---------------- K5: reduce partial maxima -> gmax, then t6 = W6a * gmax ----------------
__global__ __launch_bounds__(256) void k5_reduce_t6(
    const float* __restrict__ partials, const float* __restrict__ W6,
    float* __restrict__ t6)  // (B,256)
{
  __shared__ float sg[128];
  const int b = blockIdx.x;
  const int tid = threadIdx.x;
  if (tid < 128) {
    float m = NEGINF;
    for (int w = 0; w < 64; ++w) m = fmaxf(m, partials[(b*128 + tid)*64 + w]);
    sg[tid] = m;
  }
  __syncthreads();
  float a = 0.f;
#pragma unroll
  for (int c = 0; c < 128; c += 4) {
    float4 wv = *reinterpret_cast<const float4*>(W6 + tid*256 + c);
    a += wv.x*sg[c] + wv.y*sg[c+1] + wv.z*sg[c+2] + wv.w*sg[c+3];
  }
  t6[b*256 + tid] = a;
}

// ---------------- K6: conv6 (W6b part + t6) + bn + lrelu + W9 dot ----------------
// grid (64 nblocks, 4 b), 256 thr: p = tid&63, wave g = o-group of 64
__global__ __launch_bounds__(256) void k6_conv6_out(
    const float* __restrict__ x1, const float* __restrict__ x2,
    const float* __restrict__ W6, const float* __restrict__ t6,
    const float* __restrict__ g6, const float* __restrict__ b6,
    const float* __restrict__ m6, const float* __restrict__ v6,
    const float* __restrict__ W9,
    float* __restrict__ out)
{
  __shared__ float red[4][64];
  const int b = blockIdx.y, nb = blockIdx.x;
  const int tid = threadIdx.x;
  const int p = tid & 63;
  const int g = __builtin_amdgcn_readfirstlane(tid >> 6);
  const int n = nb*64 + p;
  float xcr[128];
#pragma unroll
  for (int c = 0; c < 64; ++c) {
    xcr[c]    = x1[(b*64 + c)*Np + n];
    xcr[64+c] = x2[(b*64 + c)*Np + n];
  }
  float oacc = 0.f;
  for (int oi = 0; oi < 64; ++oi) {
    const int o = g*64 + oi;
    const float* wr = W6 + o*256 + 128;
    float dot = t6[b*256 + o];
#pragma unroll
    for (int c = 0; c < 128; c += 4) {
      float4 wv = *reinterpret_cast<const float4*>(wr + c);
      dot += wv.x*xcr[c] + wv.y*xcr[c+1] + wv.z*xcr[c+2] + wv.w*xcr[c+3];
    }
    float hv = (dot - m6[o])*(g6[o]/sqrtf(v6[o]+EPSf)) + b6[o];
    hv = hv >= 0.f ? hv : SLOPE*hv;
    oacc += W9[o]*hv;
  }
  red[g][p] = oacc;
  __syncthreads();
  if (tid < 64)
    out[b*Np + nb*64 + tid] = red[0][tid] + red[1][tid] + red[2][tid] + red[3][tid];
}

extern "C" void kernel_launch(void* const* d_in, const int* in_sizes, int n_in,
                              void* d_out, int out_size, void* d_ws, size_t ws_size,
                              hipStream_t stream) {
  const float* x  = (const float*)d_in[0];
  const float* W1 = (const float*)d_in[1];
  const float* g1 = (const float*)d_in[2];
  const float* b1 = (const float*)d_in[3];
  const float* m1 = (const float*)d_in[4];
  const float* v1 = (const float*)d_in[5];
  const float* W2 = (const float*)d_in[6];
  const float* g2 = (const float*)d_in[7];
  const float* b2 = (const float*)d_in[8];
  const float* m2 = (const float*)d_in[9];
  const float* v2 = (const float*)d_in[10];
  const float* W5 = (const float*)d_in[11];
  const float* g5 = (const float*)d_in[12];
  const float* b5 = (const float*)d_in[13];
  const float* m5 = (const float*)d_in[14];
  const float* v5 = (const float*)d_in[15];
  const float* W6 = (const float*)d_in[16];
  const float* g6 = (const float*)d_in[17];
  const float* b6 = (const float*)d_in[18];
  const float* m6 = (const float*)d_in[19];
  const float* v6 = (const float*)d_in[20];
  const float* W9 = (const float*)d_in[21];
  float* out = (float*)d_out;

  float* F = (float*)d_ws;
  // layout (float slots):
  float*  x1    = F;                         // 1048576
  float*  xx2   = F + 1048576;               // 16384
  __bf16* x1h   = (__bf16*)(F + 1064960);    // 1048576 bf16 = 524288 slots
  __bf16* x1l   = (__bf16*)(F + 1589248);    // 524288 slots
  float*  candv = F + 2113536;               // 655360 (dead after k2b)
  int*    candi = (int*)(F + 2768896);       // 655360 (dead after k2b)
  float*  x2    = F + 2113536;               // 1048576 (aliases cand; live from k3)
  int*    idx2  = (int*)(F + 3424256);       // 327680
  float*  t6    = F + 3751936;               // 1024
  float*  parts = F + 3752960;               // 32768

  k1_knn1_edge1<<<dim3(1024,4), 256, 0, stream>>>(x, W1, g1, b1, m1, v1, x1, x1h, x1l, xx2);
  k2_knn2<<<dim3(256,2,4), 64, 0, stream>>>(x1h, x1l, xx2, candv, candi);
  k2b_merge<<<64, 256, 0, stream>>>(candv, candi, idx2);
  k3_edge2<<<dim3(1024,4), 256, 0, stream>>>(x1h, x1l, idx2, W2, g2, b2, m2, v2, x2);
  k4_conv5max<<<dim3(64,4), 256, 0, stream>>>(x1, x2, W5, g5, b5, m5, v5, parts);
  k5_reduce_t6<<<4, 256, 0, stream>>>(parts, W6, t6);
  k6_conv6_out<<<dim3(64,4), 256, 0, stream>>>(x1, x2, W6, t6, g6, b6, m6, v6, W9, out);
}

// Round 3
// 1136.533 us; speedup vs baseline: 1.9901x; 1.0366x over previous
//
#include <hip/hip_runtime.h>
#include <math.h>

#define NEGINF (-INFINITY)
constexpr int Np = 4096;
constexpr int Kn = 20;
constexpr float EPSf = 1e-5f;
constexpr float SLOPE = 0.2f;

typedef __bf16 bf16x8 __attribute__((ext_vector_type(8)));
typedef float f32x4 __attribute__((ext_vector_type(4)));
typedef unsigned long long ull;
typedef unsigned int u32;

// ---------------- K1: knn over 2-D coords + edgeconv1 (one wave per point) ----------------
__global__ __launch_bounds__(256) void k1_knn1_edge1(
    const float* __restrict__ x, const float* __restrict__ W1,
    const float* __restrict__ g1, const float* __restrict__ b1,
    const float* __restrict__ m1, const float* __restrict__ v1,
    float* __restrict__ x1, __bf16* __restrict__ x1h, __bf16* __restrict__ x1l,
    float* __restrict__ xx2)
{
  __shared__ float2 sxy[Np];
  __shared__ int stopidx[4][Kn];
  const int b = blockIdx.y;
  const int tid = threadIdx.x;
  const int w = tid >> 6, L = tid & 63;
  const int n = blockIdx.x * 4 + w;

  for (int j = tid; j < Np; j += 256)
    sxy[j] = make_float2(x[b*2*Np + j], x[b*2*Np + Np + j]);
  __syncthreads();

  const float2 cp = sxy[n];
  const float cx0 = cp.x, cx1 = cp.y;
  const float xxc = cx0*cx0 + cx1*cx1;

  float d[64];
#pragma unroll
  for (int t = 0; t < 64; ++t) {
    int j = t*64 + L;
    float2 pj = sxy[j];
    float xxj = pj.x*pj.x + pj.y*pj.y;
    float dot = cx0*pj.x + cx1*pj.y;
    float inner = -2.0f*dot;
    d[t] = (-xxc - inner) - xxj;
  }

  for (int kk = 0; kk < Kn; ++kk) {
    float bv = d[0]; int bj = L;
#pragma unroll
    for (int t = 1; t < 64; ++t) {
      int j = t*64 + L;
      if (d[t] > bv) { bv = d[t]; bj = j; }
    }
#pragma unroll
    for (int off = 1; off < 64; off <<= 1) {
      float ov = __shfl_xor(bv, off);
      int oj = __shfl_xor(bj, off);
      if (ov > bv || (ov == bv && oj < bj)) { bv = ov; bj = oj; }
    }
    if (L == 0) stopidx[w][kk] = bj;
    int mt = bj >> 6, ml = bj & 63;
    if (L == ml) {
#pragma unroll
      for (int t = 0; t < 64; ++t) if (t == mt) d[t] = NEGINF;
    }
  }

  // edgeconv1: lane = output channel o
  const int o = L;
  const float4 w1v = reinterpret_cast<const float4*>(W1)[o];
  const float sc = g1[o] / sqrtf(v1[o] + EPSf);
  const float mo = m1[o], bo = b1[o];
  float xm = NEGINF;
  for (int k = 0; k < Kn; ++k) {
    int j = stopidx[w][k];
    float2 pj = sxy[j];
    float vv = w1v.x*(pj.x-cx0) + w1v.y*(pj.y-cx1) + w1v.z*cx0 + w1v.w*cx1;
    float h = (vv - mo)*sc + bo;
    h = h >= 0.f ? h : SLOPE*h;
    xm = fmaxf(xm, h);
  }
  x1[(b*64 + o)*Np + n] = xm;
  __bf16 hb = (__bf16)xm;
  float hf = (float)hb;
  __bf16 lb = (__bf16)(xm - hf);
  size_t tbase = ((size_t)b*Np + n)*64 + o;
  x1h[tbase] = hb;
  x1l[tbase] = lb;
  float s = xm*xm;
#pragma unroll
  for (int off = 1; off < 64; off <<= 1) s += __shfl_xor(s, off);
  if (L == 0) xx2[b*Np + n] = s;
}

// ---------------- K2: knn2 — split-bf16 MFMA gram + buffered exact top-20 ----------------
// grid (256 rowblocks, 4 batches), 64 threads. Block: 16 rows x 4096 cols.
// Key = (sortable(e) << 32) | ~j  where e = 2*dot - ||x_j||^2 (row-const dropped).
__global__ __launch_bounds__(64) void k2_knn2(
    const __bf16* __restrict__ xh, const __bf16* __restrict__ xl,
    const float* __restrict__ xx2, int* __restrict__ idx2)
{
  __shared__ float sxx[Np];            // 16 KB
  __shared__ float se[16][68];         // 4.25 KB
  __shared__ ull   pbuf[64][8];        // 4 KB  per-lane push stacks
  __shared__ ull   skv[64][20];        // 10 KB final lists for merge

  const int b = blockIdx.y;
  const int n0 = blockIdx.x * 16;
  const int L = threadIdx.x;
  const int L15 = L & 15, quad = L >> 4;
  const int srow = L >> 2, sst = L & 3;

  // preload column norms
  for (int j = L*4; j < Np; j += 256)
    *reinterpret_cast<float4*>(&sxx[j]) = *reinterpret_cast<const float4*>(&xx2[b*Np + j]);

  // A fragments: rows n0..n0+15, lane holds A[m=L15][k=quad*8+j]
  const __bf16* Abase_h = xh + ((size_t)b*Np + n0)*64;
  const __bf16* Abase_l = xl + ((size_t)b*Np + n0)*64;
  bf16x8 ah0 = *reinterpret_cast<const bf16x8*>(Abase_h + L15*64 +  0 + quad*8);
  bf16x8 ah1 = *reinterpret_cast<const bf16x8*>(Abase_h + L15*64 + 32 + quad*8);
  bf16x8 al0 = *reinterpret_cast<const bf16x8*>(Abase_l + L15*64 +  0 + quad*8);
  bf16x8 al1 = *reinterpret_cast<const bf16x8*>(Abase_l + L15*64 + 32 + quad*8);

  ull kv[20];
#pragma unroll
  for (int s = 0; s < 20; ++s) kv[s] = 0ull;
  ull thresh = 0ull;
  int cnt = 0;

  __syncthreads();

  for (int tt = 0; tt < 64; ++tt) {
    const int colbase = tt * 64;

    // B fragments for 4 col-tiles
    const __bf16* Bh = xh + ((size_t)b*Np + colbase)*64;
    const __bf16* Bl = xl + ((size_t)b*Np + colbase)*64;
    bf16x8 bh[4][2], bl[4][2];
#pragma unroll
    for (int s = 0; s < 4; ++s) {
#pragma unroll
      for (int c = 0; c < 2; ++c) {
        bh[s][c] = *reinterpret_cast<const bf16x8*>(Bh + (s*16 + L15)*64 + c*32 + quad*8);
        bl[s][c] = *reinterpret_cast<const bf16x8*>(Bl + (s*16 + L15)*64 + c*32 + quad*8);
      }
    }

    f32x4 acc[4];
#pragma unroll
    for (int s = 0; s < 4; ++s) {
      acc[s] = (f32x4){0.f, 0.f, 0.f, 0.f};
      acc[s] = __builtin_amdgcn_mfma_f32_16x16x32_bf16(ah0, bh[s][0], acc[s], 0, 0, 0);
      acc[s] = __builtin_amdgcn_mfma_f32_16x16x32_bf16(ah1, bh[s][1], acc[s], 0, 0, 0);
      acc[s] = __builtin_amdgcn_mfma_f32_16x16x32_bf16(ah0, bl[s][0], acc[s], 0, 0, 0);
      acc[s] = __builtin_amdgcn_mfma_f32_16x16x32_bf16(ah1, bl[s][1], acc[s], 0, 0, 0);
      acc[s] = __builtin_amdgcn_mfma_f32_16x16x32_bf16(al0, bh[s][0], acc[s], 0, 0, 0);
      acc[s] = __builtin_amdgcn_mfma_f32_16x16x32_bf16(al1, bh[s][1], acc[s], 0, 0, 0);
    }

    __syncthreads();   // previous tile's scan finished reading se
    // C/D layout: col = L15, row = quad*4 + r
#pragma unroll
    for (int s = 0; s < 4; ++s) {
      float xc = sxx[colbase + s*16 + L15];
#pragma unroll
      for (int r = 0; r < 4; ++r)
        se[quad*4 + r][s*16 + L15] = 2.0f*acc[s][r] - xc;
    }
    __syncthreads();   // se visible

    // scan: lane covers (row srow, 16-col stripe sst)
#pragma unroll
    for (int tq = 0; tq < 4; ++tq) {
      float4 rv = *reinterpret_cast<const float4*>(&se[srow][sst*16 + tq*4]);
      const int jb = colbase + sst*16 + tq*4;
      float vals[4] = {rv.x, rv.y, rv.z, rv.w};
#pragma unroll
      for (int c = 0; c < 4; ++c) {
        u32 u = __float_as_uint(vals[c]);
        u32 hk = u ^ ((u32)((int)u >> 31) | 0x80000000u);
        ull key = ((ull)hk << 32) | (u32)~(u32)(jb + c);
        if (key > thresh) { pbuf[L][cnt] = key; cnt++; }
      }
      if (__any(cnt >= 4)) {
        // flush: insert pending keys into sorted (desc) kv[20]
#pragma unroll
        for (int f = 0; f < 8; ++f) {
          ull key = pbuf[L][f];
          if (f < cnt && key > kv[19]) {
            ull ck = key;
#pragma unroll
            for (int s = 0; s < 20; ++s) {
              bool sw = ck > kv[s];
              ull tv = kv[s];
              kv[s] = sw ? ck : kv[s];
              ck = sw ? tv : ck;
            }
          }
        }
        cnt = 0;
        ull t0 = kv[19];
        t0 = t0 > (ull)__shfl_xor((unsigned long long)t0, 1) ? t0 : (ull)__shfl_xor((unsigned long long)t0, 1);
        t0 = t0 > (ull)__shfl_xor((unsigned long long)t0, 2) ? t0 : (ull)__shfl_xor((unsigned long long)t0, 2);
        thresh = t0;
      }
    }
  }

  // final flush
#pragma unroll
  for (int f = 0; f < 8; ++f) {
    ull key = pbuf[L][f];
    if (f < cnt && key > kv[19]) {
      ull ck = key;
#pragma unroll
      for (int s = 0; s < 20; ++s) {
        bool sw = ck > kv[s];
        ull tv = kv[s];
        kv[s] = sw ? ck : kv[s];
        ck = sw ? tv : ck;
      }
    }
  }

  // dump lists, 4-way merge per row (keys unique -> plain max-merge is exact)
#pragma unroll
  for (int k = 0; k < Kn; ++k) skv[L][k] = kv[k];
  __syncthreads();
  if (L < 16) {
    const int r = L;
    int p0 = 0, p1 = 0, p2 = 0, p3 = 0;
    size_t obase = ((size_t)b*Np + n0 + r)*Kn;
    for (int k = 0; k < Kn; ++k) {
      ull v0 = skv[4*r+0][p0 < 20 ? p0 : 19]; v0 = (p0 < 20) ? v0 : 0ull;
      ull v1 = skv[4*r+1][p1 < 20 ? p1 : 19]; v1 = (p1 < 20) ? v1 : 0ull;
      ull v2 = skv[4*r+2][p2 < 20 ? p2 : 19]; v2 = (p2 < 20) ? v2 : 0ull;
      ull v3 = skv[4*r+3][p3 < 20 ? p3 : 19]; v3 = (p3 < 20) ? v3 : 0ull;
      ull best = v0; int sel = 0;
      if (v1 > best) { best = v1; sel = 1; }
      if (v2 > best) { best = v2; sel = 2; }
      if (v3 > best) { best = v3; sel = 3; }
      idx2[obase + k] = (int)~(u32)best;
      p0 += (sel == 0); p1 += (sel == 1); p2 += (sel == 2); p3 += (sel == 3);
    }
  }
}

// ---------------- K3: edgeconv2 (one wave per point, W2 rows in registers) ----------------
__global__ __launch_bounds__(256) void k3_edge2(
    const __bf16* __restrict__ xh, const __bf16* __restrict__ xl,
    const int* __restrict__ idx2,
    const float* __restrict__ W2,
    const float* __restrict__ g2, const float* __restrict__ b2,
    const float* __restrict__ m2, const float* __restrict__ v2,
    float* __restrict__ x2)
{
  __shared__ float scen[4][64];
  __shared__ float snbr[4][64];
  const int b = blockIdx.y;
  const int tid = threadIdx.x;
  const int w = tid >> 6, L = tid & 63;
  const int n = blockIdx.x*4 + w;

  float4 w2a[16], w2b[16];
#pragma unroll
  for (int q = 0; q < 16; ++q) {
    w2a[q] = reinterpret_cast<const float4*>(W2 + L*128)[q];
    w2b[q] = reinterpret_cast<const float4*>(W2 + L*128 + 64)[q];
  }
  const float sc2 = g2[L]/sqrtf(v2[L]+EPSf);
  const float m2o = m2[L], b2o = b2[L];

  float cen = (float)xh[((size_t)b*Np + n)*64 + L] + (float)xl[((size_t)b*Np + n)*64 + L];
  scen[w][L] = cen;
  __syncthreads();
  float u = 0.f, t2 = 0.f;
#pragma unroll
  for (int q = 0; q < 16; ++q) {
    float4 cv = *reinterpret_cast<const float4*>(&scen[w][q*4]);
    u  += w2a[q].x*cv.x + w2a[q].y*cv.y + w2a[q].z*cv.z + w2a[q].w*cv.w;
    t2 += w2b[q].x*cv.x + w2b[q].y*cv.y + w2b[q].z*cv.z + w2b[q].w*cv.w;
  }

  const int* ip = idx2 + ((size_t)b*Np + n)*Kn;
  float xm = NEGINF;
  int j0 = ip[0];
  float cur = (float)xh[((size_t)b*Np + j0)*64 + L] + (float)xl[((size_t)b*Np + j0)*64 + L];
  for (int k = 0; k < Kn; ++k) {
    float nxt = 0.f;
    if (k+1 < Kn) {
      int jn = ip[k+1];
      nxt = (float)xh[((size_t)b*Np + jn)*64 + L] + (float)xl[((size_t)b*Np + jn)*64 + L];
    }
    snbr[w][L] = cur;
    float a = 0.f;
#pragma unroll
    for (int q = 0; q < 16; ++q) {
      float4 nv = *reinterpret_cast<const float4*>(&snbr[w][q*4]);
      a += w2a[q].x*nv.x + w2a[q].y*nv.y + w2a[q].z*nv.z + w2a[q].w*nv.w;
    }
    float vv = a - u + t2;
    float hh = (vv - m2o)*sc2 + b2o;
    hh = hh >= 0.f ? hh : SLOPE*hh;
    xm = fmaxf(xm, hh);
    cur = nxt;
  }
  x2[(b*64 + L)*Np + n] = xm;
}

// ---------------- K4: conv5 + per-block max over n ----------------
__global__ __launch_bounds__(256) void k4_conv5max(
    const float* __restrict__ x1, const float* __restrict__ x2,
    const float* __restrict__ W5,
    const float* __restrict__ g5, const float* __restrict__ b5,
    const float* __restrict__ m5, const float* __restrict__ v5,
    float* __restrict__ partials)  // (B,128,64)
{
  const int b = blockIdx.y, nb = blockIdx.x;
  const int tid = threadIdx.x;
  const int p = tid & 63;
  const int g = __builtin_amdgcn_readfirstlane(tid >> 6);
  const int n = nb*64 + p;
  float xcr[128];
#pragma unroll
  for (int c = 0; c < 64; ++c) {
    xcr[c]    = x1[(b*64 + c)*Np + n];
    xcr[64+c] = x2[(b*64 + c)*Np + n];
  }
  for (int oi = 0; oi < 32; ++oi) {
    const int o = g*32 + oi;
    const float* wr = W5 + o*128;
    float dot = 0.f;
#pragma unroll
    for (int c = 0; c < 128; c += 4) {
      float4 wv = *reinterpret_cast<const float4*>(wr + c);
      dot += wv.x*xcr[c] + wv.y*xcr[c+1] + wv.z*xcr[c+2] + wv.w*xcr[c+3];
    }
    float hv = (dot - m5[o])*(g5[o]/sqrtf(v5[o]+EPSf)) + b5[o];
    hv = hv >= 0.f ? hv : SLOPE*hv;
#pragma unroll
    for (int off = 1; off < 64; off <<= 1) hv = fmaxf(hv, __shfl_xor(hv, off));
    if (p == 0) partials[(b*128 + o)*64 + nb] = hv;
  }
}

// ---------------- K5: reduce partial maxima -> gmax, then t6 = W6a * gmax ----------------
__global__ __launch_bounds__(256) void k5_reduce_t6(
    const float* __restrict__ partials, const float* __restrict__ W6,
    float* __restrict__ t6)  // (B,256)
{
  __shared__ float sg[128];
  const int b = blockIdx.x;
  const int tid = threadIdx.x;
  if (tid < 128) {
    float m = NEGINF;
    for (int w = 0; w < 64; ++w) m = fmaxf(m, partials[(b*128 + tid)*64 + w]);
    sg[tid] = m;
  }
  __syncthreads();
  float a = 0.f;
#pragma unroll
  for (int c = 0; c < 128; c += 4) {
    float4 wv = *reinterpret_cast<const float4*>(W6 + tid*256 + c);
    a += wv.x*sg[c] + wv.y*sg[c+1] + wv.z*sg[c+2] + wv.w*sg[c+3];
  }
  t6[b*256 + tid] = a;
}

// ---------------- K6: conv6 (W6b part + t6) + bn + lrelu + W9 dot ----------------
__global__ __launch_bounds__(256) void k6_conv6_out(
    const float* __restrict__ x1, const float* __restrict__ x2,
    const float* __restrict__ W6, const float* __restrict__ t6,
    const float* __restrict__ g6, const float* __restrict__ b6,
    const float* __restrict__ m6, const float* __restrict__ v6,
    const float* __restrict__ W9,
    float* __restrict__ out)
{
  __shared__ float red[4][64];
  const int b = blockIdx.y, nb = blockIdx.x;
  const int tid = threadIdx.x;
  const int p = tid & 63;
  const int g = __builtin_amdgcn_readfirstlane(tid >> 6);
  const int n = nb*64 + p;
  float xcr[128];
#pragma unroll
  for (int c = 0; c < 64; ++c) {
    xcr[c]    = x1[(b*64 + c)*Np + n];
    xcr[64+c] = x2[(b*64 + c)*Np + n];
  }
  float oacc = 0.f;
  for (int oi = 0; oi < 64; ++oi) {
    const int o = g*64 + oi;
    const float* wr = W6 + o*256 + 128;
    float dot = t6[b*256 + o];
#pragma unroll
    for (int c = 0; c < 128; c += 4) {
      float4 wv = *reinterpret_cast<const float4*>(wr + c);
      dot += wv.x*xcr[c] + wv.y*xcr[c+1] + wv.z*xcr[c+2] + wv.w*xcr[c+3];
    }
    float hv = (dot - m6[o])*(g6[o]/sqrtf(v6[o]+EPSf)) + b6[o];
    hv = hv >= 0.f ? hv : SLOPE*hv;
    oacc += W9[o]*hv;
  }
  red[g][p] = oacc;
  __syncthreads();
  if (tid < 64)
    out[b*Np + nb*64 + tid] = red[0][tid] + red[1][tid] + red[2][tid] + red[3][tid];
}

extern "C" void kernel_launch(void* const* d_in, const int* in_sizes, int n_in,
                              void* d_out, int out_size, void* d_ws, size_t ws_size,
                              hipStream_t stream) {
  const float* x  = (const float*)d_in[0];
  const float* W1 = (const float*)d_in[1];
  const float* g1 = (const float*)d_in[2];
  const float* b1 = (const float*)d_in[3];
  const float* m1 = (const float*)d_in[4];
  const float* v1 = (const float*)d_in[5];
  const float* W2 = (const float*)d_in[6];
  const float* g2 = (const float*)d_in[7];
  const float* b2 = (const float*)d_in[8];
  const float* m2 = (const float*)d_in[9];
  const float* v2 = (const float*)d_in[10];
  const float* W5 = (const float*)d_in[11];
  const float* g5 = (const float*)d_in[12];
  const float* b5 = (const float*)d_in[13];
  const float* m5 = (const float*)d_in[14];
  const float* v5 = (const float*)d_in[15];
  const float* W6 = (const float*)d_in[16];
  const float* g6 = (const float*)d_in[17];
  const float* b6 = (const float*)d_in[18];
  const float* m6 = (const float*)d_in[19];
  const float* v6 = (const float*)d_in[20];
  const float* W9 = (const float*)d_in[21];
  float* out = (float*)d_out;

  float* F = (float*)d_ws;
  float*  x1    = F;                         // 1048576
  float*  xx2   = F + 1048576;               // 16384
  __bf16* x1h   = (__bf16*)(F + 1064960);    // 524288 float-slots
  __bf16* x1l   = (__bf16*)(F + 1589248);    // 524288
  float*  x2    = F + 2113536;               // 1048576
  int*    idx2  = (int*)(F + 3162112);       // 327680
  float*  t6    = F + 3489792;               // 1024
  float*  parts = F + 3490816;               // 32768

  k1_knn1_edge1<<<dim3(1024,4), 256, 0, stream>>>(x, W1, g1, b1, m1, v1, x1, x1h, x1l, xx2);
  k2_knn2<<<dim3(256,4), 64, 0, stream>>>(x1h, x1l, xx2, idx2);
  k3_edge2<<<dim3(1024,4), 256, 0, stream>>>(x1h, x1l, idx2, W2, g2, b2, m2, v2, x2);
  k4_conv5max<<<dim3(64,4), 256, 0, stream>>>(x1, x2, W5, g5, b5, m5, v5, parts);
  k5_reduce_t6<<<4, 256, 0, stream>>>(parts, W6, t6);
  k6_conv6_out<<<dim3(64,4), 256, 0, stream>>>(x1, x2, W6, t6, g6, b6, m6, v6, W9, out);
}

// Round 4
// 759.601 us; speedup vs baseline: 2.9777x; 1.4962x over previous
//
#include <hip/hip_runtime.h>
#include <math.h>

#define NEGINF (-INFINITY)
constexpr int Np = 4096;
constexpr int Kn = 20;
constexpr float EPSf = 1e-5f;
constexpr float SLOPE = 0.2f;

typedef __bf16 bf16x8 __attribute__((ext_vector_type(8)));
typedef float f32x4 __attribute__((ext_vector_type(4)));
typedef unsigned long long ull;
typedef unsigned int u32;

// ---------------- K1: knn over 2-D coords + edgeconv1 (one wave per point) ----------------
__global__ __launch_bounds__(256) void k1_knn1_edge1(
    const float* __restrict__ x, const float* __restrict__ W1,
    const float* __restrict__ g1, const float* __restrict__ b1,
    const float* __restrict__ m1, const float* __restrict__ v1,
    float* __restrict__ x1, __bf16* __restrict__ x1h, __bf16* __restrict__ x1l,
    float* __restrict__ xx2)
{
  __shared__ float2 sxy[Np];
  __shared__ int stopidx[4][Kn];
  const int b = blockIdx.y;
  const int tid = threadIdx.x;
  const int w = tid >> 6, L = tid & 63;
  const int n = blockIdx.x * 4 + w;

  for (int j = tid; j < Np; j += 256)
    sxy[j] = make_float2(x[b*2*Np + j], x[b*2*Np + Np + j]);
  __syncthreads();

  const float2 cp = sxy[n];
  const float cx0 = cp.x, cx1 = cp.y;
  const float xxc = cx0*cx0 + cx1*cx1;

  float d[64];
#pragma unroll
  for (int t = 0; t < 64; ++t) {
    int j = t*64 + L;
    float2 pj = sxy[j];
    float xxj = pj.x*pj.x + pj.y*pj.y;
    float dot = cx0*pj.x + cx1*pj.y;
    float inner = -2.0f*dot;
    d[t] = (-xxc - inner) - xxj;
  }

  for (int kk = 0; kk < Kn; ++kk) {
    float bv = d[0]; int bj = L;
#pragma unroll
    for (int t = 1; t < 64; ++t) {
      int j = t*64 + L;
      if (d[t] > bv) { bv = d[t]; bj = j; }
    }
#pragma unroll
    for (int off = 1; off < 64; off <<= 1) {
      float ov = __shfl_xor(bv, off);
      int oj = __shfl_xor(bj, off);
      if (ov > bv || (ov == bv && oj < bj)) { bv = ov; bj = oj; }
    }
    if (L == 0) stopidx[w][kk] = bj;
    int mt = bj >> 6, ml = bj & 63;
    if (L == ml) {
#pragma unroll
      for (int t = 0; t < 64; ++t) if (t == mt) d[t] = NEGINF;
    }
  }

  // edgeconv1: lane = output channel o
  const int o = L;
  const float4 w1v = reinterpret_cast<const float4*>(W1)[o];
  const float sc = g1[o] / sqrtf(v1[o] + EPSf);
  const float mo = m1[o], bo = b1[o];
  float xm = NEGINF;
  for (int k = 0; k < Kn; ++k) {
    int j = stopidx[w][k];
    float2 pj = sxy[j];
    float vv = w1v.x*(pj.x-cx0) + w1v.y*(pj.y-cx1) + w1v.z*cx0 + w1v.w*cx1;
    float h = (vv - mo)*sc + bo;
    h = h >= 0.f ? h : SLOPE*h;
    xm = fmaxf(xm, h);
  }
  x1[(b*64 + o)*Np + n] = xm;
  __bf16 hb = (__bf16)xm;
  float hf = (float)hb;
  __bf16 lb = (__bf16)(xm - hf);
  size_t tbase = ((size_t)b*Np + n)*64 + o;
  x1h[tbase] = hb;
  x1l[tbase] = lb;
  float s = xm*xm;
#pragma unroll
  for (int off = 1; off < 64; off <<= 1) s += __shfl_xor(s, off);
  if (L == 0) xx2[b*Np + n] = s;
}

// ---------------- K2: knn2 — swapped-operand MFMA gram, register scan, exact top-20 -----
// grid (256 rowblocks, 4 batches), 64 threads (1 wave). Block: 16 rows x 4096 cols.
// MFMA: A = 16-col tile, B = 16 block rows -> D[n=L15 -> ROW][m=quad*4+r -> col].
// Each lane owns exactly one row: all selection state is lane-private.
// Key = (sortable(e) << 32) | ~j, e = 2*dot - ||x_j||^2.
__global__ __launch_bounds__(64) void k2_knn2(
    const __bf16* __restrict__ xh, const __bf16* __restrict__ xl,
    const float* __restrict__ xx2, int* __restrict__ idx2)
{
  __shared__ float sxx[Np];            // 16 KB
  __shared__ ull   pbuf[24][64];       // 12 KB, slot-major: conflict-free
  __shared__ ull   skv[64][21];        // 10.5 KB (pad 21 -> 4-way on dump)

  const int b = blockIdx.y;
  const int n0 = blockIdx.x * 16;
  const int L = threadIdx.x;
  const int L15 = L & 15, quad = L >> 4;

  for (int j = L*4; j < Np; j += 256)
    *reinterpret_cast<float4*>(&sxx[j]) = *reinterpret_cast<const float4*>(&xx2[b*Np + j]);

  // B operand (rows n0..n0+15), resident: B[k=quad*8+j][n=L15]
  const __bf16* Rh = xh + ((size_t)b*Np + n0)*64;
  const __bf16* Rl = xl + ((size_t)b*Np + n0)*64;
  bf16x8 rh0 = *reinterpret_cast<const bf16x8*>(Rh + L15*64 +  0 + quad*8);
  bf16x8 rh1 = *reinterpret_cast<const bf16x8*>(Rh + L15*64 + 32 + quad*8);
  bf16x8 rl0 = *reinterpret_cast<const bf16x8*>(Rl + L15*64 +  0 + quad*8);
  bf16x8 rl1 = *reinterpret_cast<const bf16x8*>(Rl + L15*64 + 32 + quad*8);

  const __bf16* Cbh = xh + (size_t)b*Np*64;
  const __bf16* Cbl = xl + (size_t)b*Np*64;

  ull kv[20];
#pragma unroll
  for (int s = 0; s < 20; ++s) kv[s] = 0ull;
  ull thresh = 0ull;
  float fthresh = NEGINF;
  int cnt = 0;

  __syncthreads();

  // A-fragment loader for one 64-col tile (4 sub-tiles of 16 cols)
  auto loadA = [&](bf16x8 (&AH)[4][2], bf16x8 (&AL)[4][2], int tt) {
    const __bf16* ph = Cbh + (size_t)(tt*64)*64;
    const __bf16* pl = Cbl + (size_t)(tt*64)*64;
#pragma unroll
    for (int s = 0; s < 4; ++s) {
      AH[s][0] = *reinterpret_cast<const bf16x8*>(ph + (s*16 + L15)*64 +  0 + quad*8);
      AH[s][1] = *reinterpret_cast<const bf16x8*>(ph + (s*16 + L15)*64 + 32 + quad*8);
      AL[s][0] = *reinterpret_cast<const bf16x8*>(pl + (s*16 + L15)*64 +  0 + quad*8);
      AL[s][1] = *reinterpret_cast<const bf16x8*>(pl + (s*16 + L15)*64 + 32 + quad*8);
    }
  };

  auto flush = [&]() {
#pragma unroll 1
    for (int f = 0; f < 24; ++f) {
      if (__all(f >= cnt)) break;
      ull key = pbuf[f][L];
      if (f < cnt && key > kv[19]) {
        ull ck = key;
#pragma unroll
        for (int s = 0; s < 20; ++s) {
          bool sw = ck > kv[s];
          ull tv = kv[s];
          kv[s] = sw ? ck : kv[s];
          ck = sw ? tv : ck;
        }
      }
    }
    cnt = 0;
    ull t = kv[19];
    ull t2 = __shfl_xor(t, 16); t = t2 > t ? t2 : t;
    t2 = __shfl_xor(t, 32);     t = t2 > t ? t2 : t;
    thresh = t;
    if (thresh != 0ull) {
      u32 hk = (u32)(thresh >> 32);
      u32 u = hk ^ ((hk >> 31) ? 0x80000000u : 0xFFFFFFFFu);
      fthresh = __uint_as_float(u);
    }
  };

  auto body = [&](bf16x8 (&AH)[4][2], bf16x8 (&AL)[4][2], int tt) {
    const int colbase = tt*64;
    f32x4 acc[4];
#pragma unroll
    for (int s = 0; s < 4; ++s) {
      acc[s] = (f32x4){0.f, 0.f, 0.f, 0.f};
      acc[s] = __builtin_amdgcn_mfma_f32_16x16x32_bf16(AH[s][0], rh0, acc[s], 0, 0, 0);
      acc[s] = __builtin_amdgcn_mfma_f32_16x16x32_bf16(AH[s][1], rh1, acc[s], 0, 0, 0);
      acc[s] = __builtin_amdgcn_mfma_f32_16x16x32_bf16(AH[s][0], rl0, acc[s], 0, 0, 0);
      acc[s] = __builtin_amdgcn_mfma_f32_16x16x32_bf16(AH[s][1], rl1, acc[s], 0, 0, 0);
      acc[s] = __builtin_amdgcn_mfma_f32_16x16x32_bf16(AL[s][0], rh0, acc[s], 0, 0, 0);
      acc[s] = __builtin_amdgcn_mfma_f32_16x16x32_bf16(AL[s][1], rh1, acc[s], 0, 0, 0);
    }
#pragma unroll
    for (int s = 0; s < 4; ++s) {
      // cols colbase + s*16 + quad*4 + r, r=0..3 -> contiguous float4 (broadcast read)
      float4 xv = *reinterpret_cast<const float4*>(&sxx[colbase + s*16 + quad*4]);
      const float xvr[4] = {xv.x, xv.y, xv.z, xv.w};
#pragma unroll
      for (int r = 0; r < 4; ++r) {
        float e = 2.0f*acc[s][r] - xvr[r];
        if (e >= fthresh) {
          u32 u = __float_as_uint(e);
          u32 hk = u ^ ((u32)((int)u >> 31) | 0x80000000u);
          int j = colbase + s*16 + quad*4 + r;
          pbuf[cnt][L] = (((ull)hk) << 32) | (u32)~(u32)j;
          ++cnt;
        }
      }
    }
    if (__any(cnt >= 8)) flush();
  };

  bf16x8 A0h[4][2], A0l[4][2], A1h[4][2], A1l[4][2];
  loadA(A0h, A0l, 0);
  for (int tt = 0; tt < 64; tt += 2) {
    loadA(A1h, A1l, tt + 1);
    body(A0h, A0l, tt);
    if (tt + 2 < 64) loadA(A0h, A0l, tt + 2);
    body(A1h, A1l, tt + 1);
  }
  flush();

  // dump per-lane lists; merge 4 quad-lists per row (keys unique -> max-merge exact)
#pragma unroll
  for (int k = 0; k < Kn; ++k) skv[L][k] = kv[k];
  __syncthreads();
  if (L < 16) {
    const int r = L;
    int p0 = 0, p1 = 0, p2 = 0, p3 = 0;
    size_t obase = ((size_t)b*Np + n0 + r)*Kn;
    for (int k = 0; k < Kn; ++k) {
      ull v0 = skv[ 0 + r][p0 < 20 ? p0 : 19]; v0 = (p0 < 20) ? v0 : 0ull;
      ull v1 = skv[16 + r][p1 < 20 ? p1 : 19]; v1 = (p1 < 20) ? v1 : 0ull;
      ull v2 = skv[32 + r][p2 < 20 ? p2 : 19]; v2 = (p2 < 20) ? v2 : 0ull;
      ull v3 = skv[48 + r][p3 < 20 ? p3 : 19]; v3 = (p3 < 20) ? v3 : 0ull;
      ull best = v0; int sel = 0;
      if (v1 > best) { best = v1; sel = 1; }
      if (v2 > best) { best = v2; sel = 2; }
      if (v3 > best) { best = v3; sel = 3; }
      idx2[obase + k] = (int)~(u32)best;
      p0 += (sel == 0); p1 += (sel == 1); p2 += (sel == 2); p3 += (sel == 3);
    }
  }
}

// ---------------- K3: edgeconv2 (one wave per point, W2 rows in registers) ----------------
__global__ __launch_bounds__(256) void k3_edge2(
    const __bf16* __restrict__ xh, const __bf16* __restrict__ xl,
    const int* __restrict__ idx2,
    const float* __restrict__ W2,
    const float* __restrict__ g2, const float* __restrict__ b2,
    const float* __restrict__ m2, const float* __restrict__ v2,
    float* __restrict__ x2)
{
  __shared__ float scen[4][64];
  __shared__ float snbr[4][64];
  const int b = blockIdx.y;
  const int tid = threadIdx.x;
  const int w = tid >> 6, L = tid & 63;
  const int n = blockIdx.x*4 + w;

  float4 w2a[16], w2b[16];
#pragma unroll
  for (int q = 0; q < 16; ++q) {
    w2a[q] = reinterpret_cast<const float4*>(W2 + L*128)[q];
    w2b[q] = reinterpret_cast<const float4*>(W2 + L*128 + 64)[q];
  }
  const float sc2 = g2[L]/sqrtf(v2[L]+EPSf);
  const float m2o = m2[L], b2o = b2[L];

  float cen = (float)xh[((size_t)b*Np + n)*64 + L] + (float)xl[((size_t)b*Np + n)*64 + L];
  scen[w][L] = cen;
  __syncthreads();
  float u = 0.f, t2 = 0.f;
#pragma unroll
  for (int q = 0; q < 16; ++q) {
    float4 cv = *reinterpret_cast<const float4*>(&scen[w][q*4]);
    u  += w2a[q].x*cv.x + w2a[q].y*cv.y + w2a[q].z*cv.z + w2a[q].w*cv.w;
    t2 += w2b[q].x*cv.x + w2b[q].y*cv.y + w2b[q].z*cv.z + w2b[q].w*cv.w;
  }

  const int* ip = idx2 + ((size_t)b*Np + n)*Kn;
  float xm = NEGINF;
  int j0 = ip[0];
  float cur = (float)xh[((size_t)b*Np + j0)*64 + L] + (float)xl[((size_t)b*Np + j0)*64 + L];
  for (int k = 0; k < Kn; ++k) {
    float nxt = 0.f;
    if (k+1 < Kn) {
      int jn = ip[k+1];
      nxt = (float)xh[((size_t)b*Np + jn)*64 + L] + (float)xl[((size_t)b*Np + jn)*64 + L];
    }
    snbr[w][L] = cur;
    float a = 0.f;
#pragma unroll
    for (int q = 0; q < 16; ++q) {
      float4 nv = *reinterpret_cast<const float4*>(&snbr[w][q*4]);
      a += w2a[q].x*nv.x + w2a[q].y*nv.y + w2a[q].z*nv.z + w2a[q].w*nv.w;
    }
    float vv = a - u + t2;
    float hh = (vv - m2o)*sc2 + b2o;
    hh = hh >= 0.f ? hh : SLOPE*hh;
    xm = fmaxf(xm, hh);
    cur = nxt;
  }
  x2[(b*64 + L)*Np + n] = xm;
}

// ---------------- K4: conv5 + per-block max over n ----------------
__global__ __launch_bounds__(256) void k4_conv5max(
    const float* __restrict__ x1, const float* __restrict__ x2,
    const float* __restrict__ W5,
    const float* __restrict__ g5, const float* __restrict__ b5,
    const float* __restrict__ m5, const float* __restrict__ v5,
    float* __restrict__ partials)  // (B,128,64)
{
  const int b = blockIdx.y, nb = blockIdx.x;
  const int tid = threadIdx.x;
  const int p = tid & 63;
  const int g = __builtin_amdgcn_readfirstlane(tid >> 6);
  const int n = nb*64 + p;
  float xcr[128];
#pragma unroll
  for (int c = 0; c < 64; ++c) {
    xcr[c]    = x1[(b*64 + c)*Np + n];
    xcr[64+c] = x2[(b*64 + c)*Np + n];
  }
  for (int oi = 0; oi < 32; ++oi) {
    const int o = g*32 + oi;
    const float* wr = W5 + o*128;
    float dot = 0.f;
#pragma unroll
    for (int c = 0; c < 128; c += 4) {
      float4 wv = *reinterpret_cast<const float4*>(wr + c);
      dot += wv.x*xcr[c] + wv.y*xcr[c+1] + wv.z*xcr[c+2] + wv.w*xcr[c+3];
    }
    float hv = (dot - m5[o])*(g5[o]/sqrtf(v5[o]+EPSf)) + b5[o];
    hv = hv >= 0.f ? hv : SLOPE*hv;
#pragma unroll
    for (int off = 1; off < 64; off <<= 1) hv = fmaxf(hv, __shfl_xor(hv, off));
    if (p == 0) partials[(b*128 + o)*64 + nb] = hv;
  }
}

// ---------------- K5: reduce partial maxima -> gmax, then t6 = W6a * gmax ----------------
__global__ __launch_bounds__(256) void k5_reduce_t6(
    const float* __restrict__ partials, const float* __restrict__ W6,
    float* __restrict__ t6)  // (B,256)
{
  __shared__ float sg[128];
  const int b = blockIdx.x;
  const int tid = threadIdx.x;
  if (tid < 128) {
    float m = NEGINF;
    for (int w = 0; w < 64; ++w) m = fmaxf(m, partials[(b*128 + tid)*64 + w]);
    sg[tid] = m;
  }
  __syncthreads();
  float a = 0.f;
#pragma unroll
  for (int c = 0; c < 128; c += 4) {
    float4 wv = *reinterpret_cast<const float4*>(W6 + tid*256 + c);
    a += wv.x*sg[c] + wv.y*sg[c+1] + wv.z*sg[c+2] + wv.w*sg[c+3];
  }
  t6[b*256 + tid] = a;
}

// ---------------- K6: conv6 (W6b part + t6) + bn + lrelu + W9 dot ----------------
__global__ __launch_bounds__(256) void k6_conv6_out(
    const float* __restrict__ x1, const float* __restrict__ x2,
    const float* __restrict__ W6, const float* __restrict__ t6,
    const float* __restrict__ g6, const float* __restrict__ b6,
    const float* __restrict__ m6, const float* __restrict__ v6,
    const float* __restrict__ W9,
    float* __restrict__ out)
{
  __shared__ float red[4][64];
  const int b = blockIdx.y, nb = blockIdx.x;
  const int tid = threadIdx.x;
  const int p = tid & 63;
  const int g = __builtin_amdgcn_readfirstlane(tid >> 6);
  const int n = nb*64 + p;
  float xcr[128];
#pragma unroll
  for (int c = 0; c < 64; ++c) {
    xcr[c]    = x1[(b*64 + c)*Np + n];
    xcr[64+c] = x2[(b*64 + c)*Np + n];
  }
  float oacc = 0.f;
  for (int oi = 0; oi < 64; ++oi) {
    const int o = g*64 + oi;
    const float* wr = W6 + o*256 + 128;
    float dot = t6[b*256 + o];
#pragma unroll
    for (int c = 0; c < 128; c += 4) {
      float4 wv = *reinterpret_cast<const float4*>(wr + c);
      dot += wv.x*xcr[c] + wv.y*xcr[c+1] + wv.z*xcr[c+2] + wv.w*xcr[c+3];
    }
    float hv = (dot - m6[o])*(g6[o]/sqrtf(v6[o]+EPSf)) + b6[o];
    hv = hv >= 0.f ? hv : SLOPE*hv;
    oacc += W9[o]*hv;
  }
  red[g][p] = oacc;
  __syncthreads();
  if (tid < 64)
    out[b*Np + nb*64 + tid] = red[0][tid] + red[1][tid] + red[2][tid] + red[3][tid];
}

extern "C" void kernel_launch(void* const* d_in, const int* in_sizes, int n_in,
                              void* d_out, int out_size, void* d_ws, size_t ws_size,
                              hipStream_t stream) {
  const float* x  = (const float*)d_in[0];
  const float* W1 = (const float*)d_in[1];
  const float* g1 = (const float*)d_in[2];
  const float* b1 = (const float*)d_in[3];
  const float* m1 = (const float*)d_in[4];
  const float* v1 = (const float*)d_in[5];
  const float* W2 = (const float*)d_in[6];
  const float* g2 = (const float*)d_in[7];
  const float* b2 = (const float*)d_in[8];
  const float* m2 = (const float*)d_in[9];
  const float* v2 = (const float*)d_in[10];
  const float* W5 = (const float*)d_in[11];
  const float* g5 = (const float*)d_in[12];
  const float* b5 = (const float*)d_in[13];
  const float* m5 = (const float*)d_in[14];
  const float* v5 = (const float*)d_in[15];
  const float* W6 = (const float*)d_in[16];
  const float* g6 = (const float*)d_in[17];
  const float* b6 = (const float*)d_in[18];
  const float* m6 = (const float*)d_in[19];
  const float* v6 = (const float*)d_in[20];
  const float* W9 = (const float*)d_in[21];
  float* out = (float*)d_out;

  float* F = (float*)d_ws;
  float*  x1    = F;                         // 1048576
  float*  xx2   = F + 1048576;               // 16384
  __bf16* x1h   = (__bf16*)(F + 1064960);    // 524288 float-slots
  __bf16* x1l   = (__bf16*)(F + 1589248);    // 524288
  float*  x2    = F + 2113536;               // 1048576
  int*    idx2  = (int*)(F + 3162112);       // 327680
  float*  t6    = F + 3489792;               // 1024
  float*  parts = F + 3490816;               // 32768

  k1_knn1_edge1<<<dim3(1024,4), 256, 0, stream>>>(x, W1, g1, b1, m1, v1, x1, x1h, x1l, xx2);
  k2_knn2<<<dim3(256,4), 64, 0, stream>>>(x1h, x1l, xx2, idx2);
  k3_edge2<<<dim3(1024,4), 256, 0, stream>>>(x1h, x1l, idx2, W2, g2, b2, m2, v2, x2);
  k4_conv5max<<<dim3(64,4), 256, 0, stream>>>(x1, x2, W5, g5, b5, m5, v5, parts);
  k5_reduce_t6<<<4, 256, 0, stream>>>(parts, W6, t6);
  k6_conv6_out<<<dim3(64,4), 256, 0, stream>>>(x1, x2, W6, t6, g6, b6, m6, v6, W9, out);
}